// Round 1
// baseline (1241.625 us; speedup 1.0000x reference)
//
#include <hip/hip_runtime.h>
#include <stdint.h>

// Problem dims (from reference)
#define D_MODEL 1024
#define D_FF    4096
#define NTOK    16384   // BATCH*SEQ = 4*4096
#define SEQ     4096

typedef __bf16 bf16x8 __attribute__((ext_vector_type(8)));
typedef float  f32x4  __attribute__((ext_vector_type(4)));

typedef __attribute__((address_space(1))) void gvoid;
typedef __attribute__((address_space(3))) void svoid;

__device__ __forceinline__ unsigned short f2bf(float f) {
  union { float f; uint32_t u; } v; v.f = f;
  uint32_t u = v.u;
  u += 0x7FFFu + ((u >> 16) & 1u);   // round-to-nearest-even
  return (unsigned short)(u >> 16);
}
__device__ __forceinline__ float bf2f(unsigned short h) {
  union { uint32_t u; float f; } v; v.u = ((uint32_t)h) << 16;
  return v.f;
}

// async global->LDS, 16B per lane (dest must be wave-uniform base + lane*16)
__device__ __forceinline__ void gload16(const void* g, void* l) {
  __builtin_amdgcn_global_load_lds((gvoid*)g, (svoid*)l, 16, 0, 0);
}

// ---------------- fp32 -> bf16 weight conversion ----------------
__global__ __launch_bounds__(256) void cvt_k(const float* __restrict__ S,
                                             unsigned short* __restrict__ D, int n4) {
  int i = blockIdx.x * 256 + threadIdx.x;
  if (i < n4) {
    float4 f = reinterpret_cast<const float4*>(S)[i];
    ushort4 o;
    o.x = f2bf(f.x); o.y = f2bf(f.y); o.z = f2bf(f.z); o.w = f2bf(f.w);
    reinterpret_cast<ushort4*>(D)[i] = o;
  }
}

// ---------------- RMSNorm (+ optional scale-gate softmax) ----------------
// one block (256 thr) per token; thread t handles d = 4t..4t+3
template<bool SG>
__global__ __launch_bounds__(256) void rmsnorm_k(
    const float* __restrict__ X, const float* __restrict__ W,
    const float* __restrict__ SGW,
    unsigned short* __restrict__ H, float* __restrict__ SCL)
{
  const int n = blockIdx.x;
  const int t = threadIdx.x;
  float4 x = reinterpret_cast<const float4*>(X + (size_t)n * D_MODEL)[t];
  float4 w = reinterpret_cast<const float4*>(W)[t];
  float4 hw;
  hw.x = x.x * w.x; hw.y = x.y * w.y; hw.z = x.z * w.z; hw.w = x.w * w.w;
  float ss = x.x*x.x + x.y*x.y + x.z*x.z + x.w*x.w;
  float p0 = 0.f, p1 = 0.f, p2 = 0.f;
  if (SG) {
    float4 s0 = reinterpret_cast<const float4*>(SGW)[t];
    float4 s1 = reinterpret_cast<const float4*>(SGW + D_MODEL)[t];
    float4 s2 = reinterpret_cast<const float4*>(SGW + 2 * D_MODEL)[t];
    p0 = hw.x*s0.x + hw.y*s0.y + hw.z*s0.z + hw.w*s0.w;
    p1 = hw.x*s1.x + hw.y*s1.y + hw.z*s1.z + hw.w*s1.w;
    p2 = hw.x*s2.x + hw.y*s2.y + hw.z*s2.z + hw.w*s2.w;
  }
  #pragma unroll
  for (int off = 32; off > 0; off >>= 1) {
    ss += __shfl_xor(ss, off);
    if (SG) {
      p0 += __shfl_xor(p0, off);
      p1 += __shfl_xor(p1, off);
      p2 += __shfl_xor(p2, off);
    }
  }
  __shared__ float red[4][4];
  const int wid = t >> 6;
  if ((t & 63) == 0) { red[wid][0] = ss; red[wid][1] = p0; red[wid][2] = p1; red[wid][3] = p2; }
  __syncthreads();
  ss = red[0][0] + red[1][0] + red[2][0] + red[3][0];
  const float r = rsqrtf(ss * (1.0f / D_MODEL) + 1e-6f);
  ushort4 h4;
  h4.x = f2bf(hw.x * r); h4.y = f2bf(hw.y * r); h4.z = f2bf(hw.z * r); h4.w = f2bf(hw.w * r);
  reinterpret_cast<ushort4*>(H + (size_t)n * D_MODEL)[t] = h4;
  if (SG && t == 0) {
    float l0 = (red[0][1] + red[1][1] + red[2][1] + red[3][1]) * r;
    float l1 = (red[0][2] + red[1][2] + red[2][2] + red[3][2]) * r;
    float l2 = (red[0][3] + red[1][3] + red[2][3] + red[3][3]) * r;
    float mx = fmaxf(l0, fmaxf(l1, l2));
    float e0 = expf(l0 - mx), e1 = expf(l1 - mx), e2 = expf(l2 - mx);
    float inv = 1.f / (e0 + e1 + e2);
    SCL[n * 3 + 0] = e0 * inv; SCL[n * 3 + 1] = e1 * inv; SCL[n * 3 + 2] = e2 * inv;
  }
}

// ---------------- multi-scale causal depthwise conv + gate mix ----------------
// XLA conv (cross-correlation, causal left-pad): out[s] = sum_j w[j]*val[s-(k-1)+j]
__global__ __launch_bounds__(256) void conv_k(
    const unsigned short* __restrict__ GV,   // [NTOK, 2048] bf16: cols 0..1023 gate, 1024..2047 val
    const float* __restrict__ SCL,           // [NTOK, 3] softmaxed scales
    const float* __restrict__ W3, const float* __restrict__ W5, const float* __restrict__ W7,
    unsigned short* __restrict__ Y)          // [NTOK, 1024] bf16
{
  const int n = blockIdx.x;
  const int t = threadIdx.x;
  const int d0 = t * 4;
  const int s = n & (SEQ - 1);
  const unsigned short* vbase = GV + (size_t)n * (2 * D_MODEL) + D_MODEL + d0;
  float v[7][4];   // v[j][i] = val[s-6+j, d0+i]
  #pragma unroll
  for (int j = 0; j < 7; ++j) {
    const int tap = 6 - j;
    if (tap <= s) {
      ushort4 u = *reinterpret_cast<const ushort4*>(vbase - (size_t)tap * (2 * D_MODEL));
      v[j][0] = bf2f(u.x); v[j][1] = bf2f(u.y); v[j][2] = bf2f(u.z); v[j][3] = bf2f(u.w);
    } else {
      v[j][0] = 0.f; v[j][1] = 0.f; v[j][2] = 0.f; v[j][3] = 0.f;
    }
  }
  ushort4 gb = *reinterpret_cast<const ushort4*>(GV + (size_t)n * (2 * D_MODEL) + d0);
  float gf[4] = { bf2f(gb.x), bf2f(gb.y), bf2f(gb.z), bf2f(gb.w) };
  const float sc0 = SCL[n * 3 + 0], sc1 = SCL[n * 3 + 1], sc2 = SCL[n * 3 + 2];
  ushort4 out;
  unsigned short o[4];
  #pragma unroll
  for (int i = 0; i < 4; ++i) {
    const int d = d0 + i;
    float c3 = W3[d*3+0]*v[4][i] + W3[d*3+1]*v[5][i] + W3[d*3+2]*v[6][i];
    float c5 = W5[d*5+0]*v[2][i] + W5[d*5+1]*v[3][i] + W5[d*5+2]*v[4][i]
             + W5[d*5+3]*v[5][i] + W5[d*5+4]*v[6][i];
    float c7 = 0.f;
    #pragma unroll
    for (int j = 0; j < 7; ++j) c7 += W7[d*7+j] * v[j][i];
    const float g = 1.f / (1.f + expf(-gf[i]));
    o[i] = f2bf((sc0 * c3 + sc1 * c5 + sc2 * c7) * g);
  }
  out.x = o[0]; out.y = o[1]; out.z = o[2]; out.w = o[3];
  reinterpret_cast<ushort4*>(Y + (size_t)n * D_MODEL)[t] = out;
}

// ---------------- BT GEMM: C[M,N] = A[M,K] * B[N,K]^T ----------------
// 128x128 tile, BK=64, 4 waves (2x2), 16x16x32 bf16 MFMA, global_load_lds width 16.
#define EPI_BF16   0   // OUT bf16 = acc
#define EPI_RES    1   // OUT f32 = RES + acc
#define EPI_SWIGLU 2   // OUT bf16 = silu(acc0) * acc1   (NB==2)

template<int NB, int EPI>
__global__ __launch_bounds__(256, NB == 2 ? 1 : 2) void gemm_bt_k(
    const unsigned short* __restrict__ A,
    const unsigned short* __restrict__ B0,
    const unsigned short* __restrict__ B1,
    const float* __restrict__ RES,
    void* __restrict__ OUT,
    int M, int N, int K)
{
  __shared__ unsigned short As[128 * 64];
  __shared__ unsigned short Bs[NB][128 * 64];

  const int tid  = threadIdx.x;
  const int lane = tid & 63;
  const int wid  = tid >> 6;
  const int wr   = wid >> 1;        // wave row (0..1) -> 64 rows
  const int wcn  = wid & 1;         // wave col (0..1) -> 64 cols
  const int m0 = blockIdx.x * 128;
  const int n0 = blockIdx.y * 128;

  f32x4 acc[NB][4][4];
  #pragma unroll
  for (int q = 0; q < NB; ++q)
    #pragma unroll
    for (int m = 0; m < 4; ++m)
      #pragma unroll
      for (int n = 0; n < 4; ++n)
        #pragma unroll
        for (int r = 0; r < 4; ++r) acc[q][m][n][r] = 0.f;

  const int srow = tid >> 3;        // 0..31
  const int sc8  = (tid & 7) * 8;   // bf16 col offset within 64

  for (int k0 = 0; k0 < K; k0 += 64) {
    __syncthreads();   // all waves done reading previous tile
    #pragma unroll
    for (int i = 0; i < 4; ++i) {
      const int row = i * 32 + srow;
      gload16(A + (size_t)(m0 + row) * K + k0 + sc8, &As[row * 64 + sc8]);
    }
    #pragma unroll
    for (int i = 0; i < 4; ++i) {
      const int row = i * 32 + srow;
      gload16(B0 + (size_t)(n0 + row) * K + k0 + sc8, &Bs[0][row * 64 + sc8]);
    }
    if (NB == 2) {
      #pragma unroll
      for (int i = 0; i < 4; ++i) {
        const int row = i * 32 + srow;
        gload16(B1 + (size_t)(n0 + row) * K + k0 + sc8, &Bs[1][row * 64 + sc8]);
      }
    }
    __syncthreads();   // compiler drains vmcnt before barrier -> LDS tile ready

    #pragma unroll
    for (int kk = 0; kk < 2; ++kk) {
      const int ko = kk * 32 + (lane >> 4) * 8;
      bf16x8 a[4], b0[4], b1[4];
      #pragma unroll
      for (int m = 0; m < 4; ++m)
        a[m] = *reinterpret_cast<const bf16x8*>(&As[(wr * 64 + m * 16 + (lane & 15)) * 64 + ko]);
      #pragma unroll
      for (int n = 0; n < 4; ++n) {
        b0[n] = *reinterpret_cast<const bf16x8*>(&Bs[0][(wcn * 64 + n * 16 + (lane & 15)) * 64 + ko]);
        if (NB == 2)
          b1[n] = *reinterpret_cast<const bf16x8*>(&Bs[1][(wcn * 64 + n * 16 + (lane & 15)) * 64 + ko]);
      }
      #pragma unroll
      for (int m = 0; m < 4; ++m)
        #pragma unroll
        for (int n = 0; n < 4; ++n) {
          acc[0][m][n] = __builtin_amdgcn_mfma_f32_16x16x32_bf16(a[m], b0[n], acc[0][m][n], 0, 0, 0);
          if (NB == 2)
            acc[1][m][n] = __builtin_amdgcn_mfma_f32_16x16x32_bf16(a[m], b1[n], acc[1][m][n], 0, 0, 0);
        }
    }
  }

  // epilogue: C/D layout col=lane&15, row=(lane>>4)*4+r  [verified mapping]
  const int cr = (lane >> 4) * 4;
  const int cc = lane & 15;
  #pragma unroll
  for (int m = 0; m < 4; ++m)
    #pragma unroll
    for (int n = 0; n < 4; ++n)
      #pragma unroll
      for (int r = 0; r < 4; ++r) {
        const int grow = m0 + wr * 64 + m * 16 + cr + r;
        const int gcol = n0 + wcn * 64 + n * 16 + cc;
        const size_t idx = (size_t)grow * N + gcol;
        const float v = acc[0][m][n][r];
        if (EPI == EPI_BF16) {
          ((unsigned short*)OUT)[idx] = f2bf(v);
        } else if (EPI == EPI_RES) {
          ((float*)OUT)[idx] = RES[idx] + v;
        } else {  // SWIGLU: silu(g)*u
          const float u = acc[1][m][n][r];
          ((unsigned short*)OUT)[idx] = f2bf(v / (1.f + expf(-v)) * u);
        }
      }
}

// ---------------- launch ----------------
extern "C" void kernel_launch(void* const* d_in, const int* in_sizes, int n_in,
                              void* d_out, int out_size, void* d_ws, size_t ws_size,
                              hipStream_t stream)
{
  const float* x    = (const float*)d_in[0];
  const float* ln1w = (const float*)d_in[1];
  const float* ln2w = (const float*)d_in[2];
  const float* wf   = (const float*)d_in[3];
  const float* wm   = (const float*)d_in[4];
  const float* wco  = (const float*)d_in[5];
  const float* sgw  = (const float*)d_in[6];
  const float* upw  = (const float*)d_in[7];   // [2048,1024]
  const float* dnw  = (const float*)d_in[8];   // [1024,1024]
  const float* wg   = (const float*)d_in[9];   // [4096,1024]
  const float* wu   = (const float*)d_in[10];  // [4096,1024]
  const float* wo   = (const float*)d_in[11];  // [1024,4096]

  char* ws = (char*)d_ws;
  size_t off = 0;
  auto alloc = [&](size_t bytes) -> void* {
    void* p = ws + off;
    off += (bytes + 255) & ~(size_t)255;
    return p;
  };
  unsigned short* wb_up = (unsigned short*)alloc((size_t)2048 * 1024 * 2);
  unsigned short* wb_dn = (unsigned short*)alloc((size_t)1024 * 1024 * 2);
  unsigned short* wb_wg = (unsigned short*)alloc((size_t)4096 * 1024 * 2);
  unsigned short* wb_wu = (unsigned short*)alloc((size_t)4096 * 1024 * 2);
  unsigned short* wb_wo = (unsigned short*)alloc((size_t)1024 * 4096 * 2);
  float*          scl   = (float*)alloc((size_t)NTOK * 3 * 4);
  unsigned short* h2b   = (unsigned short*)alloc((size_t)NTOK * D_MODEL * 2);
  // 128MB region: h | gv | y live before GEMM3; gu aliases all three afterwards
  char* big = (char*)alloc((size_t)NTOK * 4096 * 2);
  unsigned short* hb  = (unsigned short*)big;                                  // [NTOK,1024]
  unsigned short* gvb = (unsigned short*)(big + (size_t)NTOK * 1024 * 2);      // [NTOK,2048]
  unsigned short* yb  = (unsigned short*)(big + (size_t)NTOK * 3072 * 2);      // [NTOK,1024]
  unsigned short* gub = (unsigned short*)big;                                  // [NTOK,4096]
  float* x1 = (float*)d_out;  // x after first residual lives in d_out

  // weights -> bf16
  cvt_k<<<2048, 256, 0, stream>>>(upw, wb_up, 2048 * 1024 / 4);
  cvt_k<<<1024, 256, 0, stream>>>(dnw, wb_dn, 1024 * 1024 / 4);
  cvt_k<<<4096, 256, 0, stream>>>(wg,  wb_wg, 4096 * 1024 / 4);
  cvt_k<<<4096, 256, 0, stream>>>(wu,  wb_wu, 4096 * 1024 / 4);
  cvt_k<<<4096, 256, 0, stream>>>(wo,  wb_wo, 1024 * 4096 / 4);

  // 1) h = rmsnorm(x, ln1); scale_w = softmax(h @ sg_w^T)
  rmsnorm_k<true><<<NTOK, 256, 0, stream>>>(x, ln1w, sgw, hb, scl);
  // 2) gv = h @ up_w^T  [NTOK, 2048] bf16
  gemm_bt_k<1, EPI_BF16><<<dim3(128, 16), 256, 0, stream>>>(hb, wb_up, nullptr, nullptr, gvb, NTOK, 2048, 1024);
  // 3) y = (sum_k scale_k * conv_k(val)) * sigmoid(gate)
  conv_k<<<NTOK, 256, 0, stream>>>(gvb, scl, wf, wm, wco, yb);
  // 4) x1 = x + y @ down_w^T
  gemm_bt_k<1, EPI_RES><<<dim3(128, 8), 256, 0, stream>>>(yb, wb_dn, nullptr, x, x1, NTOK, 1024, 1024);
  // 5) h2 = rmsnorm(x1, ln2)
  rmsnorm_k<false><<<NTOK, 256, 0, stream>>>(x1, ln2w, nullptr, h2b, nullptr);
  // 6) gu = silu(h2 @ wg^T) * (h2 @ wu^T)  [NTOK, 4096] bf16 (fused two-B GEMM)
  gemm_bt_k<2, EPI_SWIGLU><<<dim3(128, 32), 256, 0, stream>>>(h2b, wb_wg, wb_wu, nullptr, gub, NTOK, 4096, 1024);
  // 7) out = x1 + gu @ wo^T
  gemm_bt_k<1, EPI_RES><<<dim3(128, 8), 256, 0, stream>>>(gub, wb_wo, nullptr, x1, (float*)d_out, NTOK, 1024, 4096);
}

// Round 2
// 1000.456 us; speedup vs baseline: 1.2411x; 1.2411x over previous
//
#include <hip/hip_runtime.h>
#include <stdint.h>

// Problem dims (from reference)
#define D_MODEL 1024
#define D_FF    4096
#define NTOK    16384   // BATCH*SEQ = 4*4096
#define SEQ     4096

typedef __bf16 bf16x8 __attribute__((ext_vector_type(8)));
typedef float  f32x4  __attribute__((ext_vector_type(4)));

typedef __attribute__((address_space(1))) void gvoid;
typedef __attribute__((address_space(3))) void svoid;

__device__ __forceinline__ unsigned short f2bf(float f) {
  union { float f; uint32_t u; } v; v.f = f;
  uint32_t u = v.u;
  u += 0x7FFFu + ((u >> 16) & 1u);   // round-to-nearest-even
  return (unsigned short)(u >> 16);
}
__device__ __forceinline__ float bf2f(unsigned short h) {
  union { uint32_t u; float f; } v; v.u = ((uint32_t)h) << 16;
  return v.f;
}

// async global->LDS, 16B per lane (dest must be wave-uniform base + lane*16)
__device__ __forceinline__ void gload16(const void* g, void* l) {
  __builtin_amdgcn_global_load_lds((gvoid*)g, (svoid*)l, 16, 0, 0);
}

// ---------------- fp32 -> bf16 weight conversion ----------------
__global__ __launch_bounds__(256) void cvt_k(const float* __restrict__ S,
                                             unsigned short* __restrict__ D, int n4) {
  int i = blockIdx.x * 256 + threadIdx.x;
  if (i < n4) {
    float4 f = reinterpret_cast<const float4*>(S)[i];
    ushort4 o;
    o.x = f2bf(f.x); o.y = f2bf(f.y); o.z = f2bf(f.z); o.w = f2bf(f.w);
    reinterpret_cast<ushort4*>(D)[i] = o;
  }
}

// interleave wg/wu rows: D row 2i = G[i], row 2i+1 = U[i]  (rows of length 1024)
__global__ __launch_bounds__(256) void cvt_il_k(const float* __restrict__ G,
                                                const float* __restrict__ U,
                                                unsigned short* __restrict__ D) {
  int i = blockIdx.x * 256 + threadIdx.x;      // ushort4 index; 8192*1024/4 total
  const int row = i >> 8;                      // 256 ushort4 per 1024-row
  const int c4  = i & 255;
  const float* src = ((row & 1) ? U : G) + (size_t)(row >> 1) * 1024 + c4 * 4;
  float4 f = *reinterpret_cast<const float4*>(src);
  ushort4 o;
  o.x = f2bf(f.x); o.y = f2bf(f.y); o.z = f2bf(f.z); o.w = f2bf(f.w);
  reinterpret_cast<ushort4*>(D)[i] = o;
}

// ---------------- RMSNorm (+ optional scale-gate softmax) ----------------
template<bool SG>
__global__ __launch_bounds__(256) void rmsnorm_k(
    const float* __restrict__ X, const float* __restrict__ W,
    const float* __restrict__ SGW,
    unsigned short* __restrict__ H, float* __restrict__ SCL)
{
  const int n = blockIdx.x;
  const int t = threadIdx.x;
  float4 x = reinterpret_cast<const float4*>(X + (size_t)n * D_MODEL)[t];
  float4 w = reinterpret_cast<const float4*>(W)[t];
  float4 hw;
  hw.x = x.x * w.x; hw.y = x.y * w.y; hw.z = x.z * w.z; hw.w = x.w * w.w;
  float ss = x.x*x.x + x.y*x.y + x.z*x.z + x.w*x.w;
  float p0 = 0.f, p1 = 0.f, p2 = 0.f;
  if (SG) {
    float4 s0 = reinterpret_cast<const float4*>(SGW)[t];
    float4 s1 = reinterpret_cast<const float4*>(SGW + D_MODEL)[t];
    float4 s2 = reinterpret_cast<const float4*>(SGW + 2 * D_MODEL)[t];
    p0 = hw.x*s0.x + hw.y*s0.y + hw.z*s0.z + hw.w*s0.w;
    p1 = hw.x*s1.x + hw.y*s1.y + hw.z*s1.z + hw.w*s1.w;
    p2 = hw.x*s2.x + hw.y*s2.y + hw.z*s2.z + hw.w*s2.w;
  }
  #pragma unroll
  for (int off = 32; off > 0; off >>= 1) {
    ss += __shfl_xor(ss, off);
    if (SG) {
      p0 += __shfl_xor(p0, off);
      p1 += __shfl_xor(p1, off);
      p2 += __shfl_xor(p2, off);
    }
  }
  __shared__ float red[4][4];
  const int wid = t >> 6;
  if ((t & 63) == 0) { red[wid][0] = ss; red[wid][1] = p0; red[wid][2] = p1; red[wid][3] = p2; }
  __syncthreads();
  ss = red[0][0] + red[1][0] + red[2][0] + red[3][0];
  const float r = rsqrtf(ss * (1.0f / D_MODEL) + 1e-6f);
  ushort4 h4;
  h4.x = f2bf(hw.x * r); h4.y = f2bf(hw.y * r); h4.z = f2bf(hw.z * r); h4.w = f2bf(hw.w * r);
  reinterpret_cast<ushort4*>(H + (size_t)n * D_MODEL)[t] = h4;
  if (SG && t == 0) {
    float l0 = (red[0][1] + red[1][1] + red[2][1] + red[3][1]) * r;
    float l1 = (red[0][2] + red[1][2] + red[2][2] + red[3][2]) * r;
    float l2 = (red[0][3] + red[1][3] + red[2][3] + red[3][3]) * r;
    float mx = fmaxf(l0, fmaxf(l1, l2));
    float e0 = expf(l0 - mx), e1 = expf(l1 - mx), e2 = expf(l2 - mx);
    float inv = 1.f / (e0 + e1 + e2);
    SCL[n * 3 + 0] = e0 * inv; SCL[n * 3 + 1] = e1 * inv; SCL[n * 3 + 2] = e2 * inv;
  }
}

// ---------------- multi-scale causal depthwise conv + gate mix ----------------
__global__ __launch_bounds__(256) void conv_k(
    const unsigned short* __restrict__ GV,   // [NTOK, 2048] bf16: gate | val
    const float* __restrict__ SCL,           // [NTOK, 3]
    const float* __restrict__ W3, const float* __restrict__ W5, const float* __restrict__ W7,
    unsigned short* __restrict__ Y)          // [NTOK, 1024] bf16
{
  const int n = blockIdx.x;
  const int t = threadIdx.x;
  const int d0 = t * 4;
  const int s = n & (SEQ - 1);
  const unsigned short* vbase = GV + (size_t)n * (2 * D_MODEL) + D_MODEL + d0;
  float v[7][4];
  #pragma unroll
  for (int j = 0; j < 7; ++j) {
    const int tap = 6 - j;
    if (tap <= s) {
      ushort4 u = *reinterpret_cast<const ushort4*>(vbase - (size_t)tap * (2 * D_MODEL));
      v[j][0] = bf2f(u.x); v[j][1] = bf2f(u.y); v[j][2] = bf2f(u.z); v[j][3] = bf2f(u.w);
    } else {
      v[j][0] = 0.f; v[j][1] = 0.f; v[j][2] = 0.f; v[j][3] = 0.f;
    }
  }
  ushort4 gb = *reinterpret_cast<const ushort4*>(GV + (size_t)n * (2 * D_MODEL) + d0);
  float gf[4] = { bf2f(gb.x), bf2f(gb.y), bf2f(gb.z), bf2f(gb.w) };
  const float sc0 = SCL[n * 3 + 0], sc1 = SCL[n * 3 + 1], sc2 = SCL[n * 3 + 2];
  ushort4 out;
  unsigned short o[4];
  #pragma unroll
  for (int i = 0; i < 4; ++i) {
    const int d = d0 + i;
    float c3 = W3[d*3+0]*v[4][i] + W3[d*3+1]*v[5][i] + W3[d*3+2]*v[6][i];
    float c5 = W5[d*5+0]*v[2][i] + W5[d*5+1]*v[3][i] + W5[d*5+2]*v[4][i]
             + W5[d*5+3]*v[5][i] + W5[d*5+4]*v[6][i];
    float c7 = 0.f;
    #pragma unroll
    for (int j = 0; j < 7; ++j) c7 += W7[d*7+j] * v[j][i];
    const float g = 1.f / (1.f + expf(-gf[i]));
    o[i] = f2bf((sc0 * c3 + sc1 * c5 + sc2 * c7) * g);
  }
  out.x = o[0]; out.y = o[1]; out.z = o[2]; out.w = o[3];
  reinterpret_cast<ushort4*>(Y + (size_t)n * D_MODEL)[t] = out;
}

// ---------------- BT GEMM: C[M,N] = A[M,K] * B[N,K]^T ----------------
// 128x128 tile, BK=64, 4 waves (2x2), 16x16x32 bf16 MFMA, global_load_lds width 16.
#define EPI_BF16      0   // OUT bf16 = acc
#define EPI_RES       1   // OUT f32 = RES + acc
#define EPI_SWIGLU_IL 2   // B rows interleaved g/u; OUT[M,4096] bf16 = silu(g)*u

template<int EPI>
__global__ __launch_bounds__(256, 2) void gemm_bt_k(
    const unsigned short* __restrict__ A,
    const unsigned short* __restrict__ B0,
    const float* __restrict__ RES,
    void* __restrict__ OUT,
    int M, int N, int K)
{
  __shared__ unsigned short As[128 * 64];
  __shared__ unsigned short Bs[128 * 64];

  const int tid  = threadIdx.x;
  const int lane = tid & 63;
  const int wid  = tid >> 6;
  const int wr   = wid >> 1;        // wave row (0..1) -> 64 rows
  const int wcn  = wid & 1;         // wave col (0..1) -> 64 cols
  const int m0 = blockIdx.x * 128;
  const int n0 = blockIdx.y * 128;

  f32x4 acc[4][4];
  #pragma unroll
  for (int m = 0; m < 4; ++m)
    #pragma unroll
    for (int n = 0; n < 4; ++n)
      #pragma unroll
      for (int r = 0; r < 4; ++r) acc[m][n][r] = 0.f;

  const int srow = tid >> 3;        // 0..31
  const int sc8  = (tid & 7) * 8;   // bf16 col offset within 64

  for (int k0 = 0; k0 < K; k0 += 64) {
    __syncthreads();   // all waves done reading previous tile
    #pragma unroll
    for (int i = 0; i < 4; ++i) {
      const int row = i * 32 + srow;
      gload16(A + (size_t)(m0 + row) * K + k0 + sc8, &As[row * 64 + sc8]);
    }
    #pragma unroll
    for (int i = 0; i < 4; ++i) {
      const int row = i * 32 + srow;
      gload16(B0 + (size_t)(n0 + row) * K + k0 + sc8, &Bs[row * 64 + sc8]);
    }
    __syncthreads();   // vmcnt drained before barrier -> LDS tile ready

    #pragma unroll
    for (int kk = 0; kk < 2; ++kk) {
      const int ko = kk * 32 + (lane >> 4) * 8;
      bf16x8 a[4], b[4];
      #pragma unroll
      for (int m = 0; m < 4; ++m)
        a[m] = *reinterpret_cast<const bf16x8*>(&As[(wr * 64 + m * 16 + (lane & 15)) * 64 + ko]);
      #pragma unroll
      for (int n = 0; n < 4; ++n)
        b[n] = *reinterpret_cast<const bf16x8*>(&Bs[(wcn * 64 + n * 16 + (lane & 15)) * 64 + ko]);
      #pragma unroll
      for (int m = 0; m < 4; ++m)
        #pragma unroll
        for (int n = 0; n < 4; ++n)
          acc[m][n] = __builtin_amdgcn_mfma_f32_16x16x32_bf16(a[m], b[n], acc[m][n], 0, 0, 0);
    }
  }

  // epilogue: C/D layout col=lane&15, row=(lane>>4)*4+r  [verified mapping]
  const int cr = (lane >> 4) * 4;
  const int cc = lane & 15;
  #pragma unroll
  for (int m = 0; m < 4; ++m)
    #pragma unroll
    for (int n = 0; n < 4; ++n)
      #pragma unroll
      for (int r = 0; r < 4; ++r) {
        const int grow = m0 + wr * 64 + m * 16 + cr + r;
        const int gcol = n0 + wcn * 64 + n * 16 + cc;
        const float v = acc[m][n][r];
        if (EPI == EPI_BF16) {
          ((unsigned short*)OUT)[(size_t)grow * N + gcol] = f2bf(v);
        } else if (EPI == EPI_RES) {
          const size_t idx = (size_t)grow * N + gcol;
          ((float*)OUT)[idx] = RES[idx] + v;
        } else {  // EPI_SWIGLU_IL: even cc holds g, odd cc holds u for ff=gcol>>1
          const float pv = __shfl_xor(v, 1);
          const float g = (cc & 1) ? pv : v;
          const float u = (cc & 1) ? v : pv;
          const float o = g / (1.f + expf(-g)) * u;
          unsigned int ob = f2bf(o);
          const unsigned int o2 = __shfl_xor((int)ob, 2);  // lane 4j gets ff+1's value
          if ((cc & 3) == 0) {
            const int ff = gcol >> 1;                      // even ff
            *reinterpret_cast<unsigned int*>(
                &((unsigned short*)OUT)[(size_t)grow * (D_FF) + ff]) = ob | (o2 << 16);
          }
        }
      }
}

// ---------------- launch ----------------
extern "C" void kernel_launch(void* const* d_in, const int* in_sizes, int n_in,
                              void* d_out, int out_size, void* d_ws, size_t ws_size,
                              hipStream_t stream)
{
  const float* x    = (const float*)d_in[0];
  const float* ln1w = (const float*)d_in[1];
  const float* ln2w = (const float*)d_in[2];
  const float* wf   = (const float*)d_in[3];
  const float* wm   = (const float*)d_in[4];
  const float* wco  = (const float*)d_in[5];
  const float* sgw  = (const float*)d_in[6];
  const float* upw  = (const float*)d_in[7];   // [2048,1024]
  const float* dnw  = (const float*)d_in[8];   // [1024,1024]
  const float* wg   = (const float*)d_in[9];   // [4096,1024]
  const float* wu   = (const float*)d_in[10];  // [4096,1024]
  const float* wo   = (const float*)d_in[11];  // [1024,4096]

  char* ws = (char*)d_ws;
  size_t off = 0;
  auto alloc = [&](size_t bytes) -> void* {
    void* p = ws + off;
    off += (bytes + 255) & ~(size_t)255;
    return p;
  };
  unsigned short* wb_up = (unsigned short*)alloc((size_t)2048 * 1024 * 2);
  unsigned short* wb_dn = (unsigned short*)alloc((size_t)1024 * 1024 * 2);
  unsigned short* wb_il = (unsigned short*)alloc((size_t)8192 * 1024 * 2);  // interleaved wg/wu
  unsigned short* wb_wo = (unsigned short*)alloc((size_t)1024 * 4096 * 2);
  float*          scl   = (float*)alloc((size_t)NTOK * 3 * 4);
  unsigned short* h2b   = (unsigned short*)alloc((size_t)NTOK * D_MODEL * 2);
  // 128MB region: h | gv | y live before the SwiGLU GEMM; gu aliases all three afterwards
  char* big = (char*)alloc((size_t)NTOK * 4096 * 2);
  unsigned short* hb  = (unsigned short*)big;                                  // [NTOK,1024]
  unsigned short* gvb = (unsigned short*)(big + (size_t)NTOK * 1024 * 2);      // [NTOK,2048]
  unsigned short* yb  = (unsigned short*)(big + (size_t)NTOK * 3072 * 2);      // [NTOK,1024]
  unsigned short* gub = (unsigned short*)big;                                  // [NTOK,4096]
  float* x1 = (float*)d_out;  // x after first residual lives in d_out

  // weights -> bf16
  cvt_k<<<2048, 256, 0, stream>>>(upw, wb_up, 2048 * 1024 / 4);
  cvt_k<<<1024, 256, 0, stream>>>(dnw, wb_dn, 1024 * 1024 / 4);
  cvt_il_k<<<8192, 256, 0, stream>>>(wg, wu, wb_il);
  cvt_k<<<4096, 256, 0, stream>>>(wo, wb_wo, 1024 * 4096 / 4);

  // 1) h = rmsnorm(x, ln1); scale_w = softmax(h @ sg_w^T)
  rmsnorm_k<true><<<NTOK, 256, 0, stream>>>(x, ln1w, sgw, hb, scl);
  // 2) gv = h @ up_w^T  [NTOK, 2048] bf16
  gemm_bt_k<EPI_BF16><<<dim3(128, 16), 256, 0, stream>>>(hb, wb_up, nullptr, gvb, NTOK, 2048, 1024);
  // 3) y = (sum_k scale_k * conv_k(val)) * sigmoid(gate)
  conv_k<<<NTOK, 256, 0, stream>>>(gvb, scl, wf, wm, wco, yb);
  // 4) x1 = x + y @ down_w^T
  gemm_bt_k<EPI_RES><<<dim3(128, 8), 256, 0, stream>>>(yb, wb_dn, x, x1, NTOK, 1024, 1024);
  // 5) h2 = rmsnorm(x1, ln2)
  rmsnorm_k<false><<<NTOK, 256, 0, stream>>>(x1, ln2w, nullptr, h2b, nullptr);
  // 6) gu = silu(h2 @ wg^T) * (h2 @ wu^T) via interleaved single GEMM [NTOK, 4096] bf16
  gemm_bt_k<EPI_SWIGLU_IL><<<dim3(128, 64), 256, 0, stream>>>(h2b, wb_il, nullptr, gub, NTOK, 8192, 1024);
  // 7) out = x1 + gu @ wo^T
  gemm_bt_k<EPI_RES><<<dim3(128, 8), 256, 0, stream>>>(gub, wb_wo, x1, (float*)d_out, NTOK, 1024, 4096);
}

// Round 3
// 959.286 us; speedup vs baseline: 1.2943x; 1.0429x over previous
//
#include <hip/hip_runtime.h>
#include <stdint.h>

// Problem dims (from reference)
#define D_MODEL 1024
#define D_FF    4096
#define NTOK    16384   // BATCH*SEQ = 4*4096
#define SEQ     4096

typedef __bf16 bf16x8 __attribute__((ext_vector_type(8)));
typedef float  f32x4  __attribute__((ext_vector_type(4)));

typedef __attribute__((address_space(1))) void gvoid;
typedef __attribute__((address_space(3))) void svoid;

__device__ __forceinline__ unsigned short f2bf(float f) {
  union { float f; uint32_t u; } v; v.f = f;
  uint32_t u = v.u;
  u += 0x7FFFu + ((u >> 16) & 1u);   // round-to-nearest-even
  return (unsigned short)(u >> 16);
}
__device__ __forceinline__ float bf2f(unsigned short h) {
  union { uint32_t u; float f; } v; v.u = ((uint32_t)h) << 16;
  return v.f;
}

// async global->LDS, 16B per lane (dest is wave-uniform base + lane*16)
__device__ __forceinline__ void gload16(const void* g, void* l) {
  __builtin_amdgcn_global_load_lds((gvoid*)g, (svoid*)l, 16, 0, 0);
}

// ---------------- fp32 -> bf16 weight conversion ----------------
__global__ __launch_bounds__(256) void cvt_k(const float* __restrict__ S,
                                             unsigned short* __restrict__ D, int n4) {
  int i = blockIdx.x * 256 + threadIdx.x;
  if (i < n4) {
    float4 f = reinterpret_cast<const float4*>(S)[i];
    ushort4 o;
    o.x = f2bf(f.x); o.y = f2bf(f.y); o.z = f2bf(f.z); o.w = f2bf(f.w);
    reinterpret_cast<ushort4*>(D)[i] = o;
  }
}

// interleave wg/wu rows: D row 2i = G[i], row 2i+1 = U[i]  (rows of length 1024)
__global__ __launch_bounds__(256) void cvt_il_k(const float* __restrict__ G,
                                                const float* __restrict__ U,
                                                unsigned short* __restrict__ D) {
  int i = blockIdx.x * 256 + threadIdx.x;      // ushort4 index; 8192*1024/4 total
  const int row = i >> 8;                      // 256 ushort4 per 1024-row
  const int c4  = i & 255;
  const float* src = ((row & 1) ? U : G) + (size_t)(row >> 1) * 1024 + c4 * 4;
  float4 f = *reinterpret_cast<const float4*>(src);
  ushort4 o;
  o.x = f2bf(f.x); o.y = f2bf(f.y); o.z = f2bf(f.z); o.w = f2bf(f.w);
  reinterpret_cast<ushort4*>(D)[i] = o;
}

// ---------------- RMSNorm (+ optional scale-gate softmax) ----------------
template<bool SG>
__global__ __launch_bounds__(256) void rmsnorm_k(
    const float* __restrict__ X, const float* __restrict__ W,
    const float* __restrict__ SGW,
    unsigned short* __restrict__ H, float* __restrict__ SCL)
{
  const int n = blockIdx.x;
  const int t = threadIdx.x;
  float4 x = reinterpret_cast<const float4*>(X + (size_t)n * D_MODEL)[t];
  float4 w = reinterpret_cast<const float4*>(W)[t];
  float4 hw;
  hw.x = x.x * w.x; hw.y = x.y * w.y; hw.z = x.z * w.z; hw.w = x.w * w.w;
  float ss = x.x*x.x + x.y*x.y + x.z*x.z + x.w*x.w;
  float p0 = 0.f, p1 = 0.f, p2 = 0.f;
  if (SG) {
    float4 s0 = reinterpret_cast<const float4*>(SGW)[t];
    float4 s1 = reinterpret_cast<const float4*>(SGW + D_MODEL)[t];
    float4 s2 = reinterpret_cast<const float4*>(SGW + 2 * D_MODEL)[t];
    p0 = hw.x*s0.x + hw.y*s0.y + hw.z*s0.z + hw.w*s0.w;
    p1 = hw.x*s1.x + hw.y*s1.y + hw.z*s1.z + hw.w*s1.w;
    p2 = hw.x*s2.x + hw.y*s2.y + hw.z*s2.z + hw.w*s2.w;
  }
  #pragma unroll
  for (int off = 32; off > 0; off >>= 1) {
    ss += __shfl_xor(ss, off);
    if (SG) {
      p0 += __shfl_xor(p0, off);
      p1 += __shfl_xor(p1, off);
      p2 += __shfl_xor(p2, off);
    }
  }
  __shared__ float red[4][4];
  const int wid = t >> 6;
  if ((t & 63) == 0) { red[wid][0] = ss; red[wid][1] = p0; red[wid][2] = p1; red[wid][3] = p2; }
  __syncthreads();
  ss = red[0][0] + red[1][0] + red[2][0] + red[3][0];
  const float r = rsqrtf(ss * (1.0f / D_MODEL) + 1e-6f);
  ushort4 h4;
  h4.x = f2bf(hw.x * r); h4.y = f2bf(hw.y * r); h4.z = f2bf(hw.z * r); h4.w = f2bf(hw.w * r);
  reinterpret_cast<ushort4*>(H + (size_t)n * D_MODEL)[t] = h4;
  if (SG && t == 0) {
    float l0 = (red[0][1] + red[1][1] + red[2][1] + red[3][1]) * r;
    float l1 = (red[0][2] + red[1][2] + red[2][2] + red[3][2]) * r;
    float l2 = (red[0][3] + red[1][3] + red[2][3] + red[3][3]) * r;
    float mx = fmaxf(l0, fmaxf(l1, l2));
    float e0 = expf(l0 - mx), e1 = expf(l1 - mx), e2 = expf(l2 - mx);
    float inv = 1.f / (e0 + e1 + e2);
    SCL[n * 3 + 0] = e0 * inv; SCL[n * 3 + 1] = e1 * inv; SCL[n * 3 + 2] = e2 * inv;
  }
}

// ---------------- multi-scale causal depthwise conv + gate mix ----------------
__global__ __launch_bounds__(256) void conv_k(
    const unsigned short* __restrict__ GV,   // [NTOK, 2048] bf16: gate | val
    const float* __restrict__ SCL,           // [NTOK, 3]
    const float* __restrict__ W3, const float* __restrict__ W5, const float* __restrict__ W7,
    unsigned short* __restrict__ Y)          // [NTOK, 1024] bf16
{
  const int n = blockIdx.x;
  const int t = threadIdx.x;
  const int d0 = t * 4;
  const int s = n & (SEQ - 1);
  const unsigned short* vbase = GV + (size_t)n * (2 * D_MODEL) + D_MODEL + d0;
  float v[7][4];
  #pragma unroll
  for (int j = 0; j < 7; ++j) {
    const int tap = 6 - j;
    if (tap <= s) {
      ushort4 u = *reinterpret_cast<const ushort4*>(vbase - (size_t)tap * (2 * D_MODEL));
      v[j][0] = bf2f(u.x); v[j][1] = bf2f(u.y); v[j][2] = bf2f(u.z); v[j][3] = bf2f(u.w);
    } else {
      v[j][0] = 0.f; v[j][1] = 0.f; v[j][2] = 0.f; v[j][3] = 0.f;
    }
  }
  ushort4 gb = *reinterpret_cast<const ushort4*>(GV + (size_t)n * (2 * D_MODEL) + d0);
  float gf[4] = { bf2f(gb.x), bf2f(gb.y), bf2f(gb.z), bf2f(gb.w) };
  const float sc0 = SCL[n * 3 + 0], sc1 = SCL[n * 3 + 1], sc2 = SCL[n * 3 + 2];
  ushort4 out;
  unsigned short o[4];
  #pragma unroll
  for (int i = 0; i < 4; ++i) {
    const int d = d0 + i;
    float c3 = W3[d*3+0]*v[4][i] + W3[d*3+1]*v[5][i] + W3[d*3+2]*v[6][i];
    float c5 = W5[d*5+0]*v[2][i] + W5[d*5+1]*v[3][i] + W5[d*5+2]*v[4][i]
             + W5[d*5+3]*v[5][i] + W5[d*5+4]*v[6][i];
    float c7 = 0.f;
    #pragma unroll
    for (int j = 0; j < 7; ++j) c7 += W7[d*7+j] * v[j][i];
    const float g = 1.f / (1.f + expf(-gf[i]));
    o[i] = f2bf((sc0 * c3 + sc1 * c5 + sc2 * c7) * g);
  }
  out.x = o[0]; out.y = o[1]; out.z = o[2]; out.w = o[3];
  reinterpret_cast<ushort4*>(Y + (size_t)n * D_MODEL)[t] = out;
}

// ---------------- 256x256 8-phase BT GEMM: C[M,N] = A[M,K] * B[N,K]^T ----------------
// 8 waves (2M x 4N), BK=64, 2 K-tiles/iter, 128KB LDS double-buffer.
// LDS regions per slot (16KB each): A0 (tile rows 0-127), A1 (128-255),
//   B0 (nq=0 rows: wn*64+0..31), B1 (nq=1 rows: wn*64+32..63).
// Swizzle: 16B chunk slot s of local row r holds global chunk s ^ (r&7)
//   (pre-swizzled global source on stage; XOR on ds_read) -> 2-way conflicts only.
// Schedule per iter (tiles t slot0 / t+1 slot1), 1 half staged per phase:
//   pi0: rdA(s0)+rdB0(s0)  stage (t+1).B0   mma(0,0)
//   pi1: rdB1(s0)          stage (t+2).A0   mma(0,1)
//   pi2: -                 stage (t+2).A1   mma(1,1)
//   pi3: rdB0(s0)          stage (t+2).B1   mma(1,0)  vmcnt(6)
//   pi4..pi7: same on slot1, staging (t+2).B0, (t+3).A0/A1/B1, vmcnt(6)
// vmcnt(6) leaves exactly the 3 newest half-tiles outstanding; every half is
// forced landed >=1 phase before its first ds_read (verified by accounting).

#define EPI_BF16      0   // OUT bf16 = acc
#define EPI_RES       1   // OUT f32 = RES + acc
#define EPI_SWIGLU_IL 2   // B rows interleaved g/u; OUT[M,4096] bf16 = silu(g)*u

#define STAGE_A(tt, h) do { if ((tt) < nt) { \
    char* d_ = dstBase + (((tt)&1) << 16) + ((h) << 14); \
    const unsigned short* s_ = aSrc + (size_t)((h)*128) * K + (tt)*64; \
    gload16(s_, d_); gload16(s_ + (size_t)64 * K, d_ + 8192); } } while(0)

#define STAGE_B(tt, h) do { if ((tt) < nt) { \
    char* d_ = dstBase + (((tt)&1) << 16) + 32768 + ((h) << 14); \
    const unsigned short* s_ = bSrc + (size_t)((h)*32) * K + (tt)*64; \
    gload16(s_, d_); gload16(s_ + (size_t)128 * K, d_ + 8192); } } while(0)

#define LOAD_A(sl) do { \
  _Pragma("unroll") for (int mq_ = 0; mq_ < 2; ++mq_) \
  _Pragma("unroll") for (int f_ = 0; f_ < 4; ++f_) \
  _Pragma("unroll") for (int kk_ = 0; kk_ < 2; ++kk_) \
    a[mq_*4+f_][kk_] = *reinterpret_cast<const bf16x8*>(lbase + ((sl) << 16) + (wm << 14) \
        + (mq_*64 + f_*16 + l15)*128 + (((kk_*4 + l4) ^ l7) << 4)); \
  } while(0)

#define LOAD_B(sl, h) do { \
  _Pragma("unroll") for (int e_ = 0; e_ < 2; ++e_) \
  _Pragma("unroll") for (int kk_ = 0; kk_ < 2; ++kk_) \
    b[e_][kk_] = *reinterpret_cast<const bf16x8*>(lbase + ((sl) << 16) + 32768 + ((h) << 14) \
        + (wn*32 + e_*16 + l15)*128 + (((kk_*4 + l4) ^ l7) << 4)); \
  } while(0)

#define MMAQ(MQ, NQ) do { \
  _Pragma("unroll") for (int f_ = 0; f_ < 4; ++f_) \
  _Pragma("unroll") for (int e_ = 0; e_ < 2; ++e_) { \
    acc[(MQ)*4+f_][(NQ)*2+e_] = __builtin_amdgcn_mfma_f32_16x16x32_bf16( \
        a[(MQ)*4+f_][0], b[e_][0], acc[(MQ)*4+f_][(NQ)*2+e_], 0, 0, 0); \
    acc[(MQ)*4+f_][(NQ)*2+e_] = __builtin_amdgcn_mfma_f32_16x16x32_bf16( \
        a[(MQ)*4+f_][1], b[e_][1], acc[(MQ)*4+f_][(NQ)*2+e_], 0, 0, 0); \
  } } while(0)

#define PHASE_MID() \
  __builtin_amdgcn_s_barrier(); \
  asm volatile("s_waitcnt lgkmcnt(0)" ::: "memory"); \
  __builtin_amdgcn_sched_barrier(0); \
  __builtin_amdgcn_s_setprio(1)

#define PHASE_END() \
  __builtin_amdgcn_s_setprio(0); \
  __builtin_amdgcn_s_barrier()

#define PHASE_END_VM() \
  __builtin_amdgcn_s_setprio(0); \
  asm volatile("s_waitcnt vmcnt(6)" ::: "memory"); \
  __builtin_amdgcn_s_barrier()

template<int EPI>
__global__ __launch_bounds__(512, 2) void gemm256_k(
    const unsigned short* __restrict__ A,
    const unsigned short* __restrict__ B0g,
    const float* __restrict__ RES,
    void* __restrict__ OUT,
    int M, int N, int K)
{
  __shared__ uint4 lds4[8192];   // 128 KB
  char* lbase = (char*)lds4;

  const int tid  = threadIdx.x;
  const int lane = tid & 63;
  const int wid  = tid >> 6;
  const int wm   = wid >> 2;        // 0..1
  const int wn   = wid & 3;         // 0..3
  const int l15 = lane & 15, l4 = lane >> 4, l7 = lane & 7;
  const int m0 = blockIdx.x * 256;
  const int n0 = blockIdx.y * 256;
  const int nt = K >> 6;

  // staging constants: thread covers local row r0=tid>>3 (+64 for 2nd load),
  // 16B chunk slot tid&7 which must hold global chunk (tid&7)^(r0&7).
  const int r0 = tid >> 3;
  const int kc = (tid & 7) ^ (r0 & 7);
  const unsigned short* aSrc = A + (size_t)(m0 + r0) * K + kc * 8;
  const unsigned short* bSrc = B0g + (size_t)(n0 + (r0 >> 5) * 64 + (r0 & 31)) * K + kc * 8;
  char* dstBase = lbase + tid * 16;

  f32x4 acc[8][4];
  #pragma unroll
  for (int i = 0; i < 8; ++i)
    #pragma unroll
    for (int j = 0; j < 4; ++j)
      #pragma unroll
      for (int r = 0; r < 4; ++r) acc[i][j][r] = 0.f;

  bf16x8 a[8][2], b[2][2];

  // prologue: t0 fully + t1.{A0,A1,B1}; t1.B0 comes at pi0 of iter 0
  STAGE_A(0, 0); STAGE_A(0, 1); STAGE_B(0, 0); STAGE_B(0, 1);
  STAGE_A(1, 0); STAGE_A(1, 1); STAGE_B(1, 1);
  asm volatile("s_waitcnt vmcnt(6)" ::: "memory");
  __builtin_amdgcn_s_barrier();

  for (int t = 0; t < nt; t += 2) {
    // pi0: tile t (slot0), quadrant (0,0)
    LOAD_A(0); LOAD_B(0, 0);
    STAGE_B(t + 1, 0);
    PHASE_MID(); MMAQ(0, 0); PHASE_END();
    // pi1: (0,1)
    LOAD_B(0, 1);
    STAGE_A(t + 2, 0);
    PHASE_MID(); MMAQ(0, 1); PHASE_END();
    // pi2: (1,1) — reuse a,b
    STAGE_A(t + 2, 1);
    PHASE_MID(); MMAQ(1, 1); PHASE_END();
    // pi3: (1,0)
    LOAD_B(0, 0);
    STAGE_B(t + 2, 1);
    PHASE_MID(); MMAQ(1, 0); PHASE_END_VM();
    // pi4: tile t+1 (slot1), quadrant (0,0)
    LOAD_A(1); LOAD_B(1, 0);
    STAGE_B(t + 2, 0);
    PHASE_MID(); MMAQ(0, 0); PHASE_END();
    // pi5: (0,1)
    LOAD_B(1, 1);
    STAGE_A(t + 3, 0);
    PHASE_MID(); MMAQ(0, 1); PHASE_END();
    // pi6: (1,1)
    STAGE_A(t + 3, 1);
    PHASE_MID(); MMAQ(1, 1); PHASE_END();
    // pi7: (1,0)
    LOAD_B(1, 0);
    STAGE_B(t + 3, 1);
    PHASE_MID(); MMAQ(1, 0); PHASE_END_VM();
  }

  // epilogue: C/D fragment layout col=lane&15, row=(lane>>4)*4+rr
  const int cr = (lane >> 4) * 4;
  const int cc = lane & 15;
  #pragma unroll
  for (int F = 0; F < 8; ++F)
    #pragma unroll
    for (int E = 0; E < 4; ++E)
      #pragma unroll
      for (int rr = 0; rr < 4; ++rr) {
        const int grow = m0 + wm * 128 + (F >> 2) * 64 + (F & 3) * 16 + cr + rr;
        const int gcol = n0 + wn * 64 + (E >> 1) * 32 + (E & 1) * 16 + cc;
        const float v = acc[F][E][rr];
        if (EPI == EPI_BF16) {
          ((unsigned short*)OUT)[(size_t)grow * N + gcol] = f2bf(v);
        } else if (EPI == EPI_RES) {
          const size_t idx = (size_t)grow * N + gcol;
          ((float*)OUT)[idx] = RES[idx] + v;
        } else {  // EPI_SWIGLU_IL: even cc holds g, odd cc holds u for ff=gcol>>1
          const float pv = __shfl_xor(v, 1);
          const float g = (cc & 1) ? pv : v;
          const float u = (cc & 1) ? v : pv;
          const float o = g / (1.f + expf(-g)) * u;
          unsigned int ob = f2bf(o);
          const unsigned int o2 = __shfl_xor((int)ob, 2);  // lane 4j gets ff+1's value
          if ((cc & 3) == 0) {
            const int ff = gcol >> 1;                      // even ff
            *reinterpret_cast<unsigned int*>(
                &((unsigned short*)OUT)[(size_t)grow * (D_FF) + ff]) = ob | (o2 << 16);
          }
        }
      }
}

// ---------------- launch ----------------
extern "C" void kernel_launch(void* const* d_in, const int* in_sizes, int n_in,
                              void* d_out, int out_size, void* d_ws, size_t ws_size,
                              hipStream_t stream)
{
  const float* x    = (const float*)d_in[0];
  const float* ln1w = (const float*)d_in[1];
  const float* ln2w = (const float*)d_in[2];
  const float* wf   = (const float*)d_in[3];
  const float* wm   = (const float*)d_in[4];
  const float* wco  = (const float*)d_in[5];
  const float* sgw  = (const float*)d_in[6];
  const float* upw  = (const float*)d_in[7];   // [2048,1024]
  const float* dnw  = (const float*)d_in[8];   // [1024,1024]
  const float* wg   = (const float*)d_in[9];   // [4096,1024]
  const float* wu   = (const float*)d_in[10];  // [4096,1024]
  const float* wo   = (const float*)d_in[11];  // [1024,4096]

  char* ws = (char*)d_ws;
  size_t off = 0;
  auto alloc = [&](size_t bytes) -> void* {
    void* p = ws + off;
    off += (bytes + 255) & ~(size_t)255;
    return p;
  };
  unsigned short* wb_up = (unsigned short*)alloc((size_t)2048 * 1024 * 2);
  unsigned short* wb_dn = (unsigned short*)alloc((size_t)1024 * 1024 * 2);
  unsigned short* wb_il = (unsigned short*)alloc((size_t)8192 * 1024 * 2);  // interleaved wg/wu
  unsigned short* wb_wo = (unsigned short*)alloc((size_t)1024 * 4096 * 2);
  float*          scl   = (float*)alloc((size_t)NTOK * 3 * 4);
  unsigned short* h2b   = (unsigned short*)alloc((size_t)NTOK * D_MODEL * 2);
  // 128MB region: h | gv | y live before the SwiGLU GEMM; gu aliases all three afterwards
  char* big = (char*)alloc((size_t)NTOK * 4096 * 2);
  unsigned short* hb  = (unsigned short*)big;                                  // [NTOK,1024]
  unsigned short* gvb = (unsigned short*)(big + (size_t)NTOK * 1024 * 2);      // [NTOK,2048]
  unsigned short* yb  = (unsigned short*)(big + (size_t)NTOK * 3072 * 2);      // [NTOK,1024]
  unsigned short* gub = (unsigned short*)big;                                  // [NTOK,4096]
  float* x1 = (float*)d_out;  // x after first residual lives in d_out

  // weights -> bf16
  cvt_k<<<2048, 256, 0, stream>>>(upw, wb_up, 2048 * 1024 / 4);
  cvt_k<<<1024, 256, 0, stream>>>(dnw, wb_dn, 1024 * 1024 / 4);
  cvt_il_k<<<8192, 256, 0, stream>>>(wg, wu, wb_il);
  cvt_k<<<4096, 256, 0, stream>>>(wo, wb_wo, 1024 * 4096 / 4);

  // 1) h = rmsnorm(x, ln1); scale_w = softmax(h @ sg_w^T)
  rmsnorm_k<true><<<NTOK, 256, 0, stream>>>(x, ln1w, sgw, hb, scl);
  // 2) gv = h @ up_w^T  [NTOK, 2048] bf16
  gemm256_k<EPI_BF16><<<dim3(64, 8), 512, 0, stream>>>(hb, wb_up, nullptr, gvb, NTOK, 2048, 1024);
  // 3) y = (sum_k scale_k * conv_k(val)) * sigmoid(gate)
  conv_k<<<NTOK, 256, 0, stream>>>(gvb, scl, wf, wm, wco, yb);
  // 4) x1 = x + y @ down_w^T
  gemm256_k<EPI_RES><<<dim3(64, 4), 512, 0, stream>>>(yb, wb_dn, x, x1, NTOK, 1024, 1024);
  // 5) h2 = rmsnorm(x1, ln2)
  rmsnorm_k<false><<<NTOK, 256, 0, stream>>>(x1, ln2w, nullptr, h2b, nullptr);
  // 6) gu = silu(h2 @ wg^T) * (h2 @ wu^T) via interleaved single GEMM [NTOK, 4096] bf16
  gemm256_k<EPI_SWIGLU_IL><<<dim3(64, 32), 512, 0, stream>>>(h2b, wb_il, nullptr, gub, NTOK, 8192, 1024);
  // 7) out = x1 + gu @ wo^T
  gemm256_k<EPI_RES><<<dim3(64, 4), 512, 0, stream>>>(gub, wb_wo, x1, (float*)d_out, NTOK, 1024, 4096);
}

// Round 5
// 775.643 us; speedup vs baseline: 1.6008x; 1.2368x over previous
//
#include <hip/hip_runtime.h>
#include <stdint.h>

// Problem dims (from reference)
#define D_MODEL 1024
#define D_FF    4096
#define NTOK    16384   // BATCH*SEQ = 4*4096
#define SEQ     4096

typedef __bf16 bf16x8 __attribute__((ext_vector_type(8)));
typedef float  f32x4  __attribute__((ext_vector_type(4)));

typedef __attribute__((address_space(1))) void gvoid;
typedef __attribute__((address_space(3))) void svoid;

__device__ __forceinline__ unsigned short f2bf(float f) {
  union { float f; uint32_t u; } v; v.f = f;
  uint32_t u = v.u;
  u += 0x7FFFu + ((u >> 16) & 1u);   // round-to-nearest-even
  return (unsigned short)(u >> 16);
}
__device__ __forceinline__ float bf2f(unsigned short h) {
  union { uint32_t u; float f; } v; v.u = ((uint32_t)h) << 16;
  return v.f;
}

// async global->LDS, 16B per lane (dest is wave-uniform base + lane*16)
__device__ __forceinline__ void gload16(const void* g, void* l) {
  __builtin_amdgcn_global_load_lds((gvoid*)g, (svoid*)l, 16, 0, 0);
}

__device__ __forceinline__ float fast_sigmoid(float x) {
  return __builtin_amdgcn_rcpf(1.f + __expf(-x));
}

// ---------------- fp32 -> bf16 weight conversion ----------------
__global__ __launch_bounds__(256) void cvt_k(const float* __restrict__ S,
                                             unsigned short* __restrict__ D, int n4) {
  int i = blockIdx.x * 256 + threadIdx.x;
  if (i < n4) {
    float4 f = reinterpret_cast<const float4*>(S)[i];
    ushort4 o;
    o.x = f2bf(f.x); o.y = f2bf(f.y); o.z = f2bf(f.z); o.w = f2bf(f.w);
    reinterpret_cast<ushort4*>(D)[i] = o;
  }
}

// interleave wg/wu rows: D row 2i = G[i], row 2i+1 = U[i]  (rows of length 1024)
__global__ __launch_bounds__(256) void cvt_il_k(const float* __restrict__ G,
                                                const float* __restrict__ U,
                                                unsigned short* __restrict__ D) {
  int i = blockIdx.x * 256 + threadIdx.x;      // ushort4 index; 8192*1024/4 total
  const int row = i >> 8;                      // 256 ushort4 per 1024-row
  const int c4  = i & 255;
  const float* src = ((row & 1) ? U : G) + (size_t)(row >> 1) * 1024 + c4 * 4;
  float4 f = *reinterpret_cast<const float4*>(src);
  ushort4 o;
  o.x = f2bf(f.x); o.y = f2bf(f.y); o.z = f2bf(f.z); o.w = f2bf(f.w);
  reinterpret_cast<ushort4*>(D)[i] = o;
}

// ---------------- RMSNorm (+ optional scale-gate softmax) ----------------
template<bool SG>
__global__ __launch_bounds__(256) void rmsnorm_k(
    const float* __restrict__ X, const float* __restrict__ W,
    const float* __restrict__ SGW,
    unsigned short* __restrict__ H, float* __restrict__ SCL)
{
  const int n = blockIdx.x;
  const int t = threadIdx.x;
  float4 x = reinterpret_cast<const float4*>(X + (size_t)n * D_MODEL)[t];
  float4 w = reinterpret_cast<const float4*>(W)[t];
  float4 hw;
  hw.x = x.x * w.x; hw.y = x.y * w.y; hw.z = x.z * w.z; hw.w = x.w * w.w;
  float ss = x.x*x.x + x.y*x.y + x.z*x.z + x.w*x.w;
  float p0 = 0.f, p1 = 0.f, p2 = 0.f;
  if (SG) {
    float4 s0 = reinterpret_cast<const float4*>(SGW)[t];
    float4 s1 = reinterpret_cast<const float4*>(SGW + D_MODEL)[t];
    float4 s2 = reinterpret_cast<const float4*>(SGW + 2 * D_MODEL)[t];
    p0 = hw.x*s0.x + hw.y*s0.y + hw.z*s0.z + hw.w*s0.w;
    p1 = hw.x*s1.x + hw.y*s1.y + hw.z*s1.z + hw.w*s1.w;
    p2 = hw.x*s2.x + hw.y*s2.y + hw.z*s2.z + hw.w*s2.w;
  }
  #pragma unroll
  for (int off = 32; off > 0; off >>= 1) {
    ss += __shfl_xor(ss, off);
    if (SG) {
      p0 += __shfl_xor(p0, off);
      p1 += __shfl_xor(p1, off);
      p2 += __shfl_xor(p2, off);
    }
  }
  __shared__ float red[4][4];
  const int wid = t >> 6;
  if ((t & 63) == 0) { red[wid][0] = ss; red[wid][1] = p0; red[wid][2] = p1; red[wid][3] = p2; }
  __syncthreads();
  ss = red[0][0] + red[1][0] + red[2][0] + red[3][0];
  const float r = rsqrtf(ss * (1.0f / D_MODEL) + 1e-6f);
  ushort4 h4;
  h4.x = f2bf(hw.x * r); h4.y = f2bf(hw.y * r); h4.z = f2bf(hw.z * r); h4.w = f2bf(hw.w * r);
  reinterpret_cast<ushort4*>(H + (size_t)n * D_MODEL)[t] = h4;
  if (SG && t == 0) {
    float l0 = (red[0][1] + red[1][1] + red[2][1] + red[3][1]) * r;
    float l1 = (red[0][2] + red[1][2] + red[2][2] + red[3][2]) * r;
    float l2 = (red[0][3] + red[1][3] + red[2][3] + red[3][3]) * r;
    float mx = fmaxf(l0, fmaxf(l1, l2));
    float e0 = expf(l0 - mx), e1 = expf(l1 - mx), e2 = expf(l2 - mx);
    float inv = 1.f / (e0 + e1 + e2);
    SCL[n * 3 + 0] = e0 * inv; SCL[n * 3 + 1] = e1 * inv; SCL[n * 3 + 2] = e2 * inv;
  }
}

// ---------------- multi-scale causal depthwise conv + gate mix ----------------
__global__ __launch_bounds__(256) void conv_k(
    const unsigned short* __restrict__ GV,   // [NTOK, 2048] bf16: gate | val
    const float* __restrict__ SCL,           // [NTOK, 3]
    const float* __restrict__ W3, const float* __restrict__ W5, const float* __restrict__ W7,
    unsigned short* __restrict__ Y)          // [NTOK, 1024] bf16
{
  const int n = blockIdx.x;
  const int t = threadIdx.x;
  const int d0 = t * 4;
  const int s = n & (SEQ - 1);
  const unsigned short* vbase = GV + (size_t)n * (2 * D_MODEL) + D_MODEL + d0;
  float v[7][4];
  #pragma unroll
  for (int j = 0; j < 7; ++j) {
    const int tap = 6 - j;
    if (tap <= s) {
      ushort4 u = *reinterpret_cast<const ushort4*>(vbase - (size_t)tap * (2 * D_MODEL));
      v[j][0] = bf2f(u.x); v[j][1] = bf2f(u.y); v[j][2] = bf2f(u.z); v[j][3] = bf2f(u.w);
    } else {
      v[j][0] = 0.f; v[j][1] = 0.f; v[j][2] = 0.f; v[j][3] = 0.f;
    }
  }
  ushort4 gb = *reinterpret_cast<const ushort4*>(GV + (size_t)n * (2 * D_MODEL) + d0);
  float gf[4] = { bf2f(gb.x), bf2f(gb.y), bf2f(gb.z), bf2f(gb.w) };
  const float sc0 = SCL[n * 3 + 0], sc1 = SCL[n * 3 + 1], sc2 = SCL[n * 3 + 2];
  ushort4 out;
  unsigned short o[4];
  #pragma unroll
  for (int i = 0; i < 4; ++i) {
    const int d = d0 + i;
    float c3 = W3[d*3+0]*v[4][i] + W3[d*3+1]*v[5][i] + W3[d*3+2]*v[6][i];
    float c5 = W5[d*5+0]*v[2][i] + W5[d*5+1]*v[3][i] + W5[d*5+2]*v[4][i]
             + W5[d*5+3]*v[5][i] + W5[d*5+4]*v[6][i];
    float c7 = 0.f;
    #pragma unroll
    for (int j = 0; j < 7; ++j) c7 += W7[d*7+j] * v[j][i];
    const float g = fast_sigmoid(gf[i]);
    o[i] = f2bf((sc0 * c3 + sc1 * c5 + sc2 * c7) * g);
  }
  out.x = o[0]; out.y = o[1]; out.z = o[2]; out.w = o[3];
  reinterpret_cast<ushort4*>(Y + (size_t)n * D_MODEL)[t] = out;
}

// ---------------- 256x256 8-phase BT GEMM: C[M,N] = A[M,K] * B[N,K]^T ----------------
// Inline-asm ds_read_b128 fragment reads (invisible to the compiler waitcnt
// pass -> counted vmcnt(6) survives). RACE FIX (r5): the final K-iteration is
// PEELED — its beyond-range prefetches are dropped, so vmcnt(6) would only
// guarantee 2/8 of the last tile's loads landed; the peeled copy uses
// vmcnt(0) at the pi3/pi7 boundaries instead. Steady-state loop unchanged.
// LDS layout: slot s (s<<16) | A half h (h<<14) | B at 32768 + (h<<14);
// row r: r*128 bytes; 16B chunk c holds global chunk c^(r&7) (pre-swizzled
// source on stage; XOR on read).

#define EPI_BF16      0
#define EPI_RES       1
#define EPI_SWIGLU_IL 2

#define STAGE_A(tt, h) do { if ((tt) < nt) { \
    char* d_ = dstBase + (((tt)&1) << 16) + ((h) << 14); \
    const unsigned short* s_ = aSrc + (size_t)((h)*128) * K + (tt)*64; \
    gload16(s_, d_); gload16(s_ + (size_t)64 * K, d_ + 8192); } } while(0)

#define STAGE_B(tt, h) do { if ((tt) < nt) { \
    char* d_ = dstBase + (((tt)&1) << 16) + 32768 + ((h) << 14); \
    const unsigned short* s_ = bSrc + (size_t)((h)*32) * K + (tt)*64; \
    gload16(s_, d_); gload16(s_ + (size_t)128 * K, d_ + 8192); } } while(0)

// raw ds_read_b128: base VGPR + literal offset
#define DSR(dst, base, IMM) \
  asm volatile("ds_read_b128 %0, %1 offset:" #IMM : "=v"(dst) : "v"(base))

#define LOAD_A(S) do { \
  DSR(a[0][0], aA##S##k0, 0);     DSR(a[0][1], aA##S##k1, 0); \
  DSR(a[1][0], aA##S##k0, 2048);  DSR(a[1][1], aA##S##k1, 2048); \
  DSR(a[2][0], aA##S##k0, 4096);  DSR(a[2][1], aA##S##k1, 4096); \
  DSR(a[3][0], aA##S##k0, 6144);  DSR(a[3][1], aA##S##k1, 6144); \
  DSR(a[4][0], aA##S##k0, 8192);  DSR(a[4][1], aA##S##k1, 8192); \
  DSR(a[5][0], aA##S##k0, 10240); DSR(a[5][1], aA##S##k1, 10240); \
  DSR(a[6][0], aA##S##k0, 12288); DSR(a[6][1], aA##S##k1, 12288); \
  DSR(a[7][0], aA##S##k0, 14336); DSR(a[7][1], aA##S##k1, 14336); \
} while(0)

#define LOAD_B_H0(S) do { \
  DSR(b[0][0], bB##S##k0, 0);     DSR(b[0][1], bB##S##k1, 0); \
  DSR(b[1][0], bB##S##k0, 2048);  DSR(b[1][1], bB##S##k1, 2048); } while(0)

#define LOAD_B_H1(S) do { \
  DSR(b[0][0], bB##S##k0, 16384); DSR(b[0][1], bB##S##k1, 16384); \
  DSR(b[1][0], bB##S##k0, 18432); DSR(b[1][1], bB##S##k1, 18432); } while(0)

#define MMAQ(MQ, NQ) do { \
  _Pragma("unroll") for (int f_ = 0; f_ < 4; ++f_) \
  _Pragma("unroll") for (int e_ = 0; e_ < 2; ++e_) { \
    acc[(MQ)*4+f_][(NQ)*2+e_] = __builtin_amdgcn_mfma_f32_16x16x32_bf16( \
        a[(MQ)*4+f_][0], b[e_][0], acc[(MQ)*4+f_][(NQ)*2+e_], 0, 0, 0); \
    acc[(MQ)*4+f_][(NQ)*2+e_] = __builtin_amdgcn_mfma_f32_16x16x32_bf16( \
        a[(MQ)*4+f_][1], b[e_][1], acc[(MQ)*4+f_][(NQ)*2+e_], 0, 0, 0); \
  } } while(0)

#define PHASE_MID() \
  __builtin_amdgcn_s_barrier(); \
  asm volatile("s_waitcnt lgkmcnt(0)" ::: "memory"); \
  __builtin_amdgcn_sched_barrier(0); \
  __builtin_amdgcn_s_setprio(1)

#define PHASE_END() \
  __builtin_amdgcn_s_setprio(0); \
  __builtin_amdgcn_s_barrier()

#define PHASE_END_VM() \
  __builtin_amdgcn_s_setprio(0); \
  asm volatile("s_waitcnt vmcnt(6)" ::: "memory"); \
  __builtin_amdgcn_s_barrier()

#define PHASE_END_VM0() \
  __builtin_amdgcn_s_setprio(0); \
  asm volatile("s_waitcnt vmcnt(0)" ::: "memory"); \
  __builtin_amdgcn_s_barrier()

template<int EPI>
__global__ __launch_bounds__(512, 2) void gemm256_k(
    const unsigned short* __restrict__ A,
    const unsigned short* __restrict__ B0g,
    const float* __restrict__ RES,
    void* __restrict__ OUT,
    int M, int N, int K)
{
  __shared__ uint4 lds4[8192];   // 128 KB, LDS offset 0
  char* lbase = (char*)lds4;

  const int tid  = threadIdx.x;
  const int lane = tid & 63;
  const int wid  = tid >> 6;
  const int wm   = wid >> 2;        // 0..1
  const int wn   = wid & 3;         // 0..3
  const int l15 = lane & 15, l4 = lane >> 4, l7 = lane & 7;
  const int m0 = blockIdx.x * 256;
  const int n0 = blockIdx.y * 256;
  const int nt = K >> 6;            // always even, >= 16 here

  // staging: thread covers local row r0=tid>>3 (+64 for 2nd load), chunk slot
  // tid&7 which must hold global chunk (tid&7)^(r0&7)  (pre-swizzled source).
  const int r0 = tid >> 3;
  const int kc = (tid & 7) ^ (r0 & 7);
  const unsigned short* aSrc = A + (size_t)(m0 + r0) * K + kc * 8;
  const unsigned short* bSrc = B0g + (size_t)(n0 + (r0 >> 5) * 64 + (r0 & 31)) * K + kc * 8;
  char* dstBase = lbase + tid * 16;

  // fragment-read base addresses (raw LDS byte offsets; object at offset 0)
  const unsigned colswz = (unsigned)((l4 ^ l7) << 4);
  const unsigned aA0k0 = (unsigned)((wm << 14) + l15 * 128) + colswz;
  const unsigned aA0k1 = aA0k0 ^ 0x40u;        // kk=1: chunk (4+l4)^l7 = (l4^l7)^4
  const unsigned aA1k0 = aA0k0 + 65536u;
  const unsigned aA1k1 = aA0k1 + 65536u;
  const unsigned bB0k0 = (unsigned)(32768 + (wn * 32 + l15) * 128) + colswz;
  const unsigned bB0k1 = bB0k0 ^ 0x40u;
  const unsigned bB1k0 = bB0k0 + 65536u;
  const unsigned bB1k1 = bB0k1 + 65536u;

  f32x4 acc[8][4];
  #pragma unroll
  for (int i = 0; i < 8; ++i)
    #pragma unroll
    for (int j = 0; j < 4; ++j)
      #pragma unroll
      for (int r = 0; r < 4; ++r) acc[i][j][r] = 0.f;

  bf16x8 a[8][2], b[2][2];

  // prologue: t0 fully + t1.{A0,A1,B1}; t1.B0 comes at pi0 of iter 0
  STAGE_A(0, 0); STAGE_A(0, 1); STAGE_B(0, 0); STAGE_B(0, 1);
  STAGE_A(1, 0); STAGE_A(1, 1); STAGE_B(1, 1);
  asm volatile("s_waitcnt vmcnt(6)" ::: "memory");
  __builtin_amdgcn_s_barrier();

  // -------- main loop: all t with t+2 < nt (full prefetch depth) --------
  for (int t = 0; t + 2 < nt; t += 2) {
    // pi0: tile t (slot0), quadrant (0,0)
    LOAD_A(0); LOAD_B_H0(0);
    STAGE_B(t + 1, 0);
    PHASE_MID(); MMAQ(0, 0); PHASE_END();
    // pi1: (0,1)
    LOAD_B_H1(0);
    STAGE_A(t + 2, 0);
    PHASE_MID(); MMAQ(0, 1); PHASE_END();
    // pi2: (1,1) — reuse a,b
    STAGE_A(t + 2, 1);
    PHASE_MID(); MMAQ(1, 1); PHASE_END();
    // pi3: (1,0)
    LOAD_B_H0(0);
    STAGE_B(t + 2, 1);
    PHASE_MID(); MMAQ(1, 0); PHASE_END_VM();
    // pi4: tile t+1 (slot1), quadrant (0,0)
    LOAD_A(1); LOAD_B_H0(1);
    STAGE_B(t + 2, 0);
    PHASE_MID(); MMAQ(0, 0); PHASE_END();
    // pi5: (0,1)
    LOAD_B_H1(1);
    STAGE_A(t + 3, 0);
    PHASE_MID(); MMAQ(0, 1); PHASE_END();
    // pi6: (1,1)
    STAGE_A(t + 3, 1);
    PHASE_MID(); MMAQ(1, 1); PHASE_END();
    // pi7: (1,0)
    LOAD_B_H0(1);
    STAGE_B(t + 3, 1);
    PHASE_MID(); MMAQ(1, 0); PHASE_END_VM();
  }

  // -------- peeled final iteration (t = nt-2): no beyond-range stages;
  // queue is shallow so use vmcnt(0) at the tile boundary --------
  {
    // pi0: tile nt-2 (slot0) — staged & landed by previous iter's pi7 vmcnt(6)
    LOAD_A(0); LOAD_B_H0(0);
    STAGE_B(nt - 1, 0);
    PHASE_MID(); MMAQ(0, 0); PHASE_END();
    // pi1
    LOAD_B_H1(0);
    PHASE_MID(); MMAQ(0, 1); PHASE_END();
    // pi2
    PHASE_MID(); MMAQ(1, 1); PHASE_END();
    // pi3 — drain everything so tile nt-1 is fully resident before pi4
    LOAD_B_H0(0);
    PHASE_MID(); MMAQ(1, 0); PHASE_END_VM0();
    // pi4: tile nt-1 (slot1)
    LOAD_A(1); LOAD_B_H0(1);
    PHASE_MID(); MMAQ(0, 0); PHASE_END();
    // pi5
    LOAD_B_H1(1);
    PHASE_MID(); MMAQ(0, 1); PHASE_END();
    // pi6
    PHASE_MID(); MMAQ(1, 1); PHASE_END();
    // pi7
    LOAD_B_H0(1);
    PHASE_MID(); MMAQ(1, 0); PHASE_END();
  }

  // keep LDS stores observable (never taken; M>0 always) — prevents DCE of
  // global_load_lds since no compiler-visible LDS reads remain.
  if (M < -1) ((float*)OUT)[tid] = ((float*)lds4)[tid];

  // epilogue: C/D fragment layout col=lane&15, row=(lane>>4)*4+rr
  const int cr = (lane >> 4) * 4;
  const int cc = lane & 15;
  #pragma unroll
  for (int F = 0; F < 8; ++F)
    #pragma unroll
    for (int E = 0; E < 4; ++E)
      #pragma unroll
      for (int rr = 0; rr < 4; ++rr) {
        const int grow = m0 + wm * 128 + (F >> 2) * 64 + (F & 3) * 16 + cr + rr;
        const int gcol = n0 + wn * 64 + (E >> 1) * 32 + (E & 1) * 16 + cc;
        const float v = acc[F][E][rr];
        if (EPI == EPI_BF16) {
          ((unsigned short*)OUT)[(size_t)grow * N + gcol] = f2bf(v);
        } else if (EPI == EPI_RES) {
          const size_t idx = (size_t)grow * N + gcol;
          ((float*)OUT)[idx] = RES[idx] + v;
        } else {  // EPI_SWIGLU_IL: even cc holds g, odd cc holds u for ff=gcol>>1
          const float pv = __shfl_xor(v, 1);
          const float g = (cc & 1) ? pv : v;
          const float u = (cc & 1) ? v : pv;
          const float o = g * fast_sigmoid(g) * u;
          unsigned int ob = f2bf(o);
          const unsigned int o2 = __shfl_xor((int)ob, 2);  // lane 4j gets ff+1's value
          if ((cc & 3) == 0) {
            const int ff = gcol >> 1;                      // even ff
            *reinterpret_cast<unsigned int*>(
                &((unsigned short*)OUT)[(size_t)grow * (D_FF) + ff]) = ob | (o2 << 16);
          }
        }
      }
}

// ---------------- launch ----------------
extern "C" void kernel_launch(void* const* d_in, const int* in_sizes, int n_in,
                              void* d_out, int out_size, void* d_ws, size_t ws_size,
                              hipStream_t stream)
{
  const float* x    = (const float*)d_in[0];
  const float* ln1w = (const float*)d_in[1];
  const float* ln2w = (const float*)d_in[2];
  const float* wf   = (const float*)d_in[3];
  const float* wm   = (const float*)d_in[4];
  const float* wco  = (const float*)d_in[5];
  const float* sgw  = (const float*)d_in[6];
  const float* upw  = (const float*)d_in[7];   // [2048,1024]
  const float* dnw  = (const float*)d_in[8];   // [1024,1024]
  const float* wg   = (const float*)d_in[9];   // [4096,1024]
  const float* wu   = (const float*)d_in[10];  // [4096,1024]
  const float* wo   = (const float*)d_in[11];  // [1024,4096]

  char* ws = (char*)d_ws;
  size_t off = 0;
  auto alloc = [&](size_t bytes) -> void* {
    void* p = ws + off;
    off += (bytes + 255) & ~(size_t)255;
    return p;
  };
  unsigned short* wb_up = (unsigned short*)alloc((size_t)2048 * 1024 * 2);
  unsigned short* wb_dn = (unsigned short*)alloc((size_t)1024 * 1024 * 2);
  unsigned short* wb_il = (unsigned short*)alloc((size_t)8192 * 1024 * 2);  // interleaved wg/wu
  unsigned short* wb_wo = (unsigned short*)alloc((size_t)1024 * 4096 * 2);
  float*          scl   = (float*)alloc((size_t)NTOK * 3 * 4);
  unsigned short* h2b   = (unsigned short*)alloc((size_t)NTOK * D_MODEL * 2);
  // 128MB region: h | gv | y live before the SwiGLU GEMM; gu aliases all three afterwards
  char* big = (char*)alloc((size_t)NTOK * 4096 * 2);
  unsigned short* hb  = (unsigned short*)big;                                  // [NTOK,1024]
  unsigned short* gvb = (unsigned short*)(big + (size_t)NTOK * 1024 * 2);      // [NTOK,2048]
  unsigned short* yb  = (unsigned short*)(big + (size_t)NTOK * 3072 * 2);      // [NTOK,1024]
  unsigned short* gub = (unsigned short*)big;                                  // [NTOK,4096]
  float* x1 = (float*)d_out;  // x after first residual lives in d_out

  // weights -> bf16
  cvt_k<<<2048, 256, 0, stream>>>(upw, wb_up, 2048 * 1024 / 4);
  cvt_k<<<1024, 256, 0, stream>>>(dnw, wb_dn, 1024 * 1024 / 4);
  cvt_il_k<<<8192, 256, 0, stream>>>(wg, wu, wb_il);
  cvt_k<<<4096, 256, 0, stream>>>(wo, wb_wo, 1024 * 4096 / 4);

  // 1) h = rmsnorm(x, ln1); scale_w = softmax(h @ sg_w^T)
  rmsnorm_k<true><<<NTOK, 256, 0, stream>>>(x, ln1w, sgw, hb, scl);
  // 2) gv = h @ up_w^T  [NTOK, 2048] bf16
  gemm256_k<EPI_BF16><<<dim3(64, 8), 512, 0, stream>>>(hb, wb_up, nullptr, gvb, NTOK, 2048, 1024);
  // 3) y = (sum_k scale_k * conv_k(val)) * sigmoid(gate)
  conv_k<<<NTOK, 256, 0, stream>>>(gvb, scl, wf, wm, wco, yb);
  // 4) x1 = x + y @ down_w^T
  gemm256_k<EPI_RES><<<dim3(64, 4), 512, 0, stream>>>(yb, wb_dn, x, x1, NTOK, 1024, 1024);
  // 5) h2 = rmsnorm(x1, ln2)
  rmsnorm_k<false><<<NTOK, 256, 0, stream>>>(x1, ln2w, nullptr, h2b, nullptr);
  // 6) gu = silu(h2 @ wg^T) * (h2 @ wu^T) via interleaved single GEMM [NTOK, 4096] bf16
  gemm256_k<EPI_SWIGLU_IL><<<dim3(64, 32), 512, 0, stream>>>(h2b, wb_il, nullptr, gub, NTOK, 8192, 1024);
  // 7) out = x1 + gu @ wo^T
  gemm256_k<EPI_RES><<<dim3(64, 4), 512, 0, stream>>>(gub, wb_wo, x1, (float*)d_out, NTOK, 1024, 4096);
}